// Round 1
// baseline (250.641 us; speedup 1.0000x reference)
//
#include <hip/hip_runtime.h>

// ---------------------------------------------------------------------------
// Fused attention block: qkv = x@Wqkv+b; per-head softmax(q k^T/8 + keybias) v;
// out = attn@Wproj+b.  B=4 N=2048 C=768 H=12 HD=64.
// Internal compute bf16 MFMA (16x16x32), fp32 accumulate.
// ---------------------------------------------------------------------------

typedef short short8 __attribute__((ext_vector_type(8)));
typedef float f32x4 __attribute__((ext_vector_type(4)));

#define GLB_AS(p) ((const __attribute__((address_space(1))) void*)(p))
#define LDS_AS(p) ((__attribute__((address_space(3))) void*)(p))

__device__ __forceinline__ void gload_lds16(const void* g, void* l) {
  // dest = wave-uniform LDS base + lane*16 (m97 fast path)
  __builtin_amdgcn_global_load_lds(GLB_AS(g), LDS_AS(l), 16, 0, 0);
}

__device__ __forceinline__ f32x4 mfma16(short8 a, short8 b, f32x4 c) {
  return __builtin_amdgcn_mfma_f32_16x16x32_bf16(a, b, c, 0, 0, 0);
}

__device__ __forceinline__ unsigned short f2bf(float f) {
  union { float f; unsigned u; } v; v.f = f;
  unsigned r = v.u + 0x7fffu + ((v.u >> 16) & 1u);
  return (unsigned short)(r >> 16);
}

// --------------------------- pre-pass kernels ------------------------------

__global__ __launch_bounds__(256) void cvt_f32_bf16(const float* __restrict__ in,
                                                    unsigned short* __restrict__ out,
                                                    int n8) {
  int i = blockIdx.x * 256 + threadIdx.x;
  if (i >= n8) return;
  const float4* p = (const float4*)in + 2 * (size_t)i;
  float4 a = p[0], c = p[1];
  short8 r;
  r[0] = (short)f2bf(a.x); r[1] = (short)f2bf(a.y); r[2] = (short)f2bf(a.z); r[3] = (short)f2bf(a.w);
  r[4] = (short)f2bf(c.x); r[5] = (short)f2bf(c.y); r[6] = (short)f2bf(c.z); r[7] = (short)f2bf(c.w);
  ((short8*)out)[i] = r;
}

// transpose + convert: src fp32 [R][C] -> dst bf16 [C][R]
__global__ __launch_bounds__(256) void tr_cvt_f32_bf16(const float* __restrict__ src,
                                                       unsigned short* __restrict__ dst,
                                                       int R, int C) {
  __shared__ float t[32][33];
  int tx = threadIdx.x & 31, ty = threadIdx.x >> 5;
  int c0 = blockIdx.x * 32, r0 = blockIdx.y * 32;
#pragma unroll
  for (int i = 0; i < 32; i += 8)
    t[ty + i][tx] = src[(size_t)(r0 + ty + i) * C + c0 + tx];
  __syncthreads();
#pragma unroll
  for (int i = 0; i < 32; i += 8)
    dst[(size_t)(c0 + ty + i) * R + r0 + tx] = f2bf(t[tx][ty + i]);
}

// per-head bf16 transpose: src [48][2048][64] -> dst [48][64][2048]
__global__ __launch_bounds__(256) void tr_bf16_head(const unsigned short* __restrict__ src,
                                                    unsigned short* __restrict__ dst) {
  __shared__ unsigned short t[32][33];
  int tx = threadIdx.x & 31, ty = threadIdx.x >> 5;
  size_t hb = (size_t)blockIdx.z * (2048 * 64);
  int c0 = blockIdx.x * 32, r0 = blockIdx.y * 32;
#pragma unroll
  for (int i = 0; i < 32; i += 8)
    t[ty + i][tx] = src[hb + (size_t)(r0 + ty + i) * 64 + c0 + tx];
  __syncthreads();
#pragma unroll
  for (int i = 0; i < 32; i += 8)
    dst[hb + (size_t)(c0 + ty + i) * 2048 + r0 + tx] = t[tx][ty + i];
}

// ------------------------------- GEMM --------------------------------------
// C[M,N] = A[M,K] * Bt[N,K]^T, 128x128 tile, BK=64, 4 waves (2x2), m97 structure.
// EPI=0: qkv epilogue (bias, q-scale, scatter to q/k/v [B,H,N,64])
// EPI=1: proj epilogue (bias, fp32 out [M][768])
template <int EPI>
__global__ __launch_bounds__(256, 2) void gemm_bt(
    const unsigned short* __restrict__ A, const unsigned short* __restrict__ Bt,
    const float* __restrict__ bias, float* __restrict__ outf,
    unsigned short* __restrict__ qo, unsigned short* __restrict__ ko,
    unsigned short* __restrict__ vo, int K) {
  __shared__ __align__(16) unsigned short As[128 * 64];
  __shared__ __align__(16) unsigned short Bs[128 * 64];
  const int tid = threadIdx.x;
  const int lane = tid & 63, wid = tid >> 6;
  const int lr = lane & 15, lg = lane >> 4;
  const int bm = blockIdx.x, bn = blockIdx.y;
  const int wr = (wid >> 1) * 64, wc = (wid & 1) * 64;

  // staging: 16 chunks of 1KB per tile; wave w covers chunks w*4..w*4+3.
  // LDS dest linear; source k-group pre-XOR-swizzled (rule #21).
  const unsigned short* ap[4];
  const unsigned short* bp[4];
  unsigned loff[4];
#pragma unroll
  for (int i = 0; i < 4; ++i) {
    int c = wid * 4 + i;
    int r = c * 8 + (lane >> 3);
    int gs = (lane & 7) ^ (r & 7);
    ap[i] = A + (size_t)(bm * 128 + r) * K + gs * 8;
    bp[i] = Bt + (size_t)(bn * 128 + r) * K + gs * 8;
    loff[i] = (unsigned)c * 1024;
  }

  f32x4 acc[4][4] = {};
  const int nt = K >> 6;
  for (int t = 0; t < nt; ++t) {
#pragma unroll
    for (int i = 0; i < 4; ++i) {
      gload_lds16(ap[i], (char*)As + loff[i]);
      gload_lds16(bp[i], (char*)Bs + loff[i]);
      ap[i] += 64;
      bp[i] += 64;
    }
    __syncthreads();
#pragma unroll
    for (int kkk = 0; kkk < 2; ++kkk) {
      short8 af[4], bf[4];
#pragma unroll
      for (int mf = 0; mf < 4; ++mf) {
        int r = wr + mf * 16 + lr;
        int g = kkk * 4 + lg;
        af[mf] = *(const short8*)((const char*)As + r * 128 + ((g ^ (r & 7)) << 4));
      }
#pragma unroll
      for (int nf = 0; nf < 4; ++nf) {
        int r = wc + nf * 16 + lr;
        int g = kkk * 4 + lg;
        bf[nf] = *(const short8*)((const char*)Bs + r * 128 + ((g ^ (r & 7)) << 4));
      }
#pragma unroll
      for (int mf = 0; mf < 4; ++mf)
#pragma unroll
        for (int nf = 0; nf < 4; ++nf)
          acc[mf][nf] = mfma16(af[mf], bf[nf], acc[mf][nf]);
    }
    __syncthreads();
  }

  const int colbase = bn * 128 + wc;
  float bv[4];
#pragma unroll
  for (int nf = 0; nf < 4; ++nf) bv[nf] = bias[colbase + nf * 16 + lr];

  if constexpr (EPI == 0) {
#pragma unroll
    for (int nf = 0; nf < 4; ++nf) {
      int col = colbase + nf * 16 + lr;
      int which = col / 768;
      int rem = col - which * 768;
      int h = rem >> 6, d = rem & 63;
#pragma unroll
      for (int mf = 0; mf < 4; ++mf) {
#pragma unroll
        for (int j = 0; j < 4; ++j) {
          int row = bm * 128 + wr + mf * 16 + lg * 4 + j;
          int bb = row >> 11, nn = row & 2047;
          float v = acc[mf][nf][j] + bv[nf];
          size_t off = (((size_t)bb * 12 + h) * 2048 + nn) * 64 + d;
          if (which == 0)
            qo[off] = f2bf(v * 0.125f);  // fold 1/sqrt(64) into Q
          else if (which == 1)
            ko[off] = f2bf(v);
          else
            vo[off] = f2bf(v);
        }
      }
    }
  } else {
#pragma unroll
    for (int mf = 0; mf < 4; ++mf) {
#pragma unroll
      for (int j = 0; j < 4; ++j) {
        int row = bm * 128 + wr + mf * 16 + lg * 4 + j;
#pragma unroll
        for (int nf = 0; nf < 4; ++nf) {
          int col = colbase + nf * 16 + lr;
          outf[(size_t)row * 768 + col] = acc[mf][nf][j] + bv[nf];
        }
      }
    }
  }
}

// --------------------------- flash attention -------------------------------
// grid (16 qblocks, 48 heads), 256 thr. Per block: 128 q-rows, 4 waves x 32 rows.
// K tiles of 64 keys; online softmax with key-side bias; P via wave-private
// swizzled LDS; V consumed from pre-transposed Vt [64][2048].
__global__ __launch_bounds__(256, 2) void attn_fused(
    const unsigned short* __restrict__ Q, const unsigned short* __restrict__ Kx,
    const unsigned short* __restrict__ Vt, const float* __restrict__ klb,
    unsigned short* __restrict__ Ao) {
  __shared__ __align__(16) unsigned short Ks[64 * 64];
  __shared__ __align__(16) unsigned short Vs[64 * 64];
  __shared__ __align__(16) unsigned short Ps[4 * 32 * 64];
  const int tid = threadIdx.x, lane = tid & 63, wid = tid >> 6;
  const int lr = lane & 15, lg = lane >> 4;
  const int qb = blockIdx.x, bh = blockIdx.y;
  const int b = bh / 12, h = bh - b * 12;
  const size_t hoff = (size_t)bh * (2048 * 64);
  const unsigned short* Qh = Q + hoff;
  const unsigned short* Kh = Kx + hoff;
  const unsigned short* Vh = Vt + hoff;  // [64][2048]
  const float* kb = klb + b * 2048;

  // Q fragments live in registers for the whole kernel
  short8 qf[2][2];
#pragma unroll
  for (int mf = 0; mf < 2; ++mf)
#pragma unroll
    for (int kkk = 0; kkk < 2; ++kkk) {
      int qr = qb * 128 + wid * 32 + mf * 16 + lr;
      qf[mf][kkk] = *(const short8*)(Qh + (size_t)qr * 64 + kkk * 32 + lg * 8);
    }

  const int c0 = wid * 2, c1 = wid * 2 + 1;
  const int r0s = c0 * 8 + (lane >> 3), r1s = c1 * 8 + (lane >> 3);
  const int g0 = (lane & 7) ^ (r0s & 7), g1 = (lane & 7) ^ (r1s & 7);

  f32x4 o[2][4] = {};
  float mrun[2][4], lrun[2][4];
#pragma unroll
  for (int mf = 0; mf < 2; ++mf)
#pragma unroll
    for (int j = 0; j < 4; ++j) { mrun[mf][j] = -1e30f; lrun[mf][j] = 0.f; }

  const unsigned pbase = wid * 4096;  // wave-private 32x64 bf16 P tile

  for (int t = 0; t < 32; ++t) {
    const int kt0 = t * 64;
    gload_lds16(Kh + (size_t)(kt0 + r0s) * 64 + g0 * 8, (char*)Ks + c0 * 1024);
    gload_lds16(Kh + (size_t)(kt0 + r1s) * 64 + g1 * 8, (char*)Ks + c1 * 1024);
    gload_lds16(Vh + (size_t)r0s * 2048 + kt0 + g0 * 8, (char*)Vs + c0 * 1024);
    gload_lds16(Vh + (size_t)r1s * 2048 + kt0 + g1 * 8, (char*)Vs + c1 * 1024);
    __syncthreads();

    float bv[4];
#pragma unroll
    for (int nf = 0; nf < 4; ++nf) bv[nf] = kb[kt0 + nf * 16 + lr];

    // S = Q K^T (Q pre-scaled); S[q][kt]
    f32x4 s[2][4] = {};
#pragma unroll
    for (int kkk = 0; kkk < 2; ++kkk) {
      short8 kf[4];
#pragma unroll
      for (int nf = 0; nf < 4; ++nf) {
        int r = nf * 16 + lr, g = kkk * 4 + lg;
        kf[nf] = *(const short8*)((const char*)Ks + r * 128 + ((g ^ (r & 7)) << 4));
      }
#pragma unroll
      for (int mf = 0; mf < 2; ++mf)
#pragma unroll
        for (int nf = 0; nf < 4; ++nf)
          s[mf][nf] = mfma16(qf[mf][kkk], kf[nf], s[mf][nf]);
    }

    // key-side bias
#pragma unroll
    for (int mf = 0; mf < 2; ++mf)
#pragma unroll
      for (int nf = 0; nf < 4; ++nf)
#pragma unroll
        for (int j = 0; j < 4; ++j) s[mf][nf][j] += bv[nf];

    // wave-parallel online softmax (rows live in 16-lane groups)
#pragma unroll
    for (int mf = 0; mf < 2; ++mf)
#pragma unroll
      for (int j = 0; j < 4; ++j) {
        float mx = fmaxf(fmaxf(s[mf][0][j], s[mf][1][j]), fmaxf(s[mf][2][j], s[mf][3][j]));
        mx = fmaxf(mx, __shfl_xor(mx, 1));
        mx = fmaxf(mx, __shfl_xor(mx, 2));
        mx = fmaxf(mx, __shfl_xor(mx, 4));
        mx = fmaxf(mx, __shfl_xor(mx, 8));
        float mnew = fmaxf(mrun[mf][j], mx);
        float al = __expf(mrun[mf][j] - mnew);
        mrun[mf][j] = mnew;
        float rs = 0.f;
#pragma unroll
        for (int nf = 0; nf < 4; ++nf) {
          float p = __expf(s[mf][nf][j] - mnew);
          s[mf][nf][j] = p;
          rs += p;
        }
        rs += __shfl_xor(rs, 1);
        rs += __shfl_xor(rs, 2);
        rs += __shfl_xor(rs, 4);
        rs += __shfl_xor(rs, 8);
        lrun[mf][j] = lrun[mf][j] * al + rs;
#pragma unroll
        for (int nf = 0; nf < 4; ++nf) o[mf][nf][j] *= al;
      }

    // P -> bf16 -> wave-private LDS (swizzled)
#pragma unroll
    for (int mf = 0; mf < 2; ++mf)
#pragma unroll
      for (int nf = 0; nf < 4; ++nf)
#pragma unroll
        for (int j = 0; j < 4; ++j) {
          int qr = mf * 16 + lg * 4 + j;
          int col = nf * 16 + lr;
          unsigned byteo = pbase + qr * 128 + (((col >> 3) ^ (qr & 7)) << 4) + ((col & 7) << 1);
          *(unsigned short*)((char*)Ps + byteo) = f2bf(s[mf][nf][j]);
        }

    // O += P V
#pragma unroll
    for (int kkk = 0; kkk < 2; ++kkk) {
      short8 pf[2], vf[4];
#pragma unroll
      for (int mf = 0; mf < 2; ++mf) {
        int qr = mf * 16 + lr, g = kkk * 4 + lg;
        pf[mf] = *(const short8*)((const char*)Ps + pbase + qr * 128 + ((g ^ (qr & 7)) << 4));
      }
#pragma unroll
      for (int nf = 0; nf < 4; ++nf) {
        int r = nf * 16 + lr, g = kkk * 4 + lg;
        vf[nf] = *(const short8*)((const char*)Vs + r * 128 + ((g ^ (r & 7)) << 4));
      }
#pragma unroll
      for (int mf = 0; mf < 2; ++mf)
#pragma unroll
        for (int nf = 0; nf < 4; ++nf)
          o[mf][nf] = mfma16(pf[mf], vf[nf], o[mf][nf]);
    }
    __syncthreads();
  }

  // epilogue: O / l -> bf16 -> attn_out [B][N][C]
#pragma unroll
  for (int mf = 0; mf < 2; ++mf)
#pragma unroll
    for (int j = 0; j < 4; ++j) {
      float inv = 1.f / lrun[mf][j];
      int qr = qb * 128 + wid * 32 + mf * 16 + lg * 4 + j;
#pragma unroll
      for (int nf = 0; nf < 4; ++nf) {
        int d = nf * 16 + lr;
        Ao[((size_t)b * 2048 + qr) * 768 + h * 64 + d] = f2bf(o[mf][nf][j] * inv);
      }
    }
}

// ------------------------------ launcher -----------------------------------

extern "C" void kernel_launch(void* const* d_in, const int* in_sizes, int n_in,
                              void* d_out, int out_size, void* d_ws, size_t ws_size,
                              hipStream_t stream) {
  (void)in_sizes; (void)n_in; (void)out_size; (void)ws_size;
  const float* x = (const float*)d_in[0];
  const float* wqkv = (const float*)d_in[1];
  const float* bqkv = (const float*)d_in[2];
  const float* wproj = (const float*)d_in[3];
  const float* bproj = (const float*)d_in[4];
  const float* klb = (const float*)d_in[5];
  float* out = (float*)d_out;
  char* ws = (char*)d_ws;

  const size_t SZ = (size_t)8192 * 768 * 2;  // 12,582,912 B (one [B,N,C] bf16)
  unsigned short* xb = (unsigned short*)(ws);
  unsigned short* wqkvT = (unsigned short*)(ws + SZ);
  unsigned short* wprojT = (unsigned short*)(ws + SZ + 3538944);
  unsigned short* qbuf = (unsigned short*)(ws + SZ + 3538944 + 1179648);
  unsigned short* kbuf = (unsigned short*)(ws + SZ + 3538944 + 1179648 + SZ);
  unsigned short* vbuf = (unsigned short*)(ws + SZ + 3538944 + 1179648 + 2 * SZ);
  unsigned short* vtbuf = (unsigned short*)(ws + SZ + 3538944 + 1179648 + 3 * SZ);
  unsigned short* aob = xb;  // xb dead after gemm1; reuse for attention output

  cvt_f32_bf16<<<dim3(3072), dim3(256), 0, stream>>>(x, xb, 786432);
  tr_cvt_f32_bf16<<<dim3(72, 24), dim3(256), 0, stream>>>(wqkv, wqkvT, 768, 2304);
  tr_cvt_f32_bf16<<<dim3(24, 24), dim3(256), 0, stream>>>(wproj, wprojT, 768, 768);
  gemm_bt<0><<<dim3(64, 18), dim3(256), 0, stream>>>(xb, wqkvT, bqkv, nullptr,
                                                     qbuf, kbuf, vbuf, 768);
  tr_bf16_head<<<dim3(2, 64, 48), dim3(256), 0, stream>>>(vbuf, vtbuf);
  attn_fused<<<dim3(16, 48), dim3(256), 0, stream>>>(qbuf, kbuf, vtbuf, klb, aob);
  gemm_bt<1><<<dim3(64, 6), dim3(256), 0, stream>>>(aob, wprojT, bproj, out,
                                                    nullptr, nullptr, nullptr, 768);
}